// Round 1
// baseline (1163.717 us; speedup 1.0000x reference)
//
#include <hip/hip_runtime.h>
#include <math.h>

// IDMForwardSim: B=8192, T=40, H=100, LAT=10, ADIM=2. fp32 baseline (R1).
// Structure: prep kernel zero-pads Wh/Wx/b/attW into d_ws ([k][512] layout,
// gates padded 100->128). Main kernel: 512 blocks x 256 threads, NB=16
// batches/block. Per step: register-tiled GEMM (thread = 4 batches x 8
// strided cols), z exchange via LDS, state threads apply LSTM gates, one
// thread per batch runs the IDM/attention scalar chain.

#define B_TOT 8192
#define T_STEPS 40
#define NB 16

// ws layout (float offsets)
#define WH_OFF 0        // [100][512]
#define WX_OFF 51200    // [102][512]
#define BP_OFF 103424   // [512]
#define AW_OFF 103936   // [128]
#define WS_FLOATS 104064

__device__ __forceinline__ float sigf(float x) { return 1.f / (1.f + __expf(-x)); }
__device__ __forceinline__ float tanhf_(float x) {
  float xc = fminf(fmaxf(x, -15.f), 15.f);
  float e = __expf(2.f * xc);
  return (e - 1.f) / (e + 1.f);
}

__global__ __launch_bounds__(256) void idm_prep(
    const float* __restrict__ lstm_Wx, const float* __restrict__ lstm_Wh,
    const float* __restrict__ lstm_b, const float* __restrict__ att_W,
    float* __restrict__ ws)
{
  int i = blockIdx.x * 256 + threadIdx.x;
  if (i < 51200) {  // Wh_pad [100][512]
    int k = i >> 9, col = i & 511, g = col >> 7, j = col & 127;
    ws[WH_OFF + i] = (j < 100) ? lstm_Wh[k * 400 + g * 100 + j] : 0.f;
  }
  if (i < 52224) {  // Wx_pad [102][512]
    int k = i >> 9, col = i & 511, g = col >> 7, j = col & 127;
    ws[WX_OFF + i] = (j < 100) ? lstm_Wx[k * 400 + g * 100 + j] : 0.f;
  }
  if (i < 512) {    // bias pad
    int g = i >> 7, j = i & 127;
    ws[BP_OFF + i] = (j < 100) ? lstm_b[g * 100 + j] : 0.f;
  }
  if (i < 128) {    // att_W pad
    ws[AW_OFF + i] = (i < 100) ? att_W[i] : 0.f;
  }
}

__global__ __launch_bounds__(256, 2) void idm_main(
    const float* __restrict__ z_att,
    const float* __restrict__ idm_params,
    const float* __restrict__ idm_s,
    const float* __restrict__ sdv_acts,
    const float* __restrict__ linear_W,
    const float* __restrict__ linear_b,
    const float* __restrict__ att_b,
    const float* __restrict__ noise_f,
    const float* __restrict__ noise_m,
    const float* __restrict__ ws,
    float* __restrict__ out)
{
  __shared__ float hT[128][16];   // h transposed: hT[j][b_local]
  __shared__ float zS[NB][512];   // z exchange tile
  __shared__ float part[NB][16];  // att-dot partials

  const int tid = threadIdx.x;
  // GEMM role: 4 batch-quads x 64 col-groups; thread owns 4 batches x 8 strided cols
  const int bq = tid >> 6;            // 0..3
  const int gj = tid & 63;            // 0..63, cols = gj + 64*m
  // State role: thread owns 1 batch x 8 contiguous j
  const int sb = bq * 4 + ((tid >> 4) & 3);  // 0..15
  const int soct = tid & 15;                 // 0..15
  const int sj0 = soct * 8;

  const int bg_state = blockIdx.x * NB + sb;
  const int b0 = blockIdx.x * NB + bq * 4;

  const float* __restrict__ WH = ws + WH_OFF;
  const float* __restrict__ WX = ws + WX_OFF;
  const float* __restrict__ BP = ws + BP_OFF;
  const float* __restrict__ AW = ws + AW_OFF;

  // ---------------- Phase A: att_proj -> h0 = c0 ----------------
  float creg[8];
  {
    float za[10];
    #pragma unroll
    for (int l = 0; l < 10; ++l) za[l] = z_att[bg_state * 10 + l];
    #pragma unroll
    for (int jj = 0; jj < 8; ++jj) {
      int j = sj0 + jj;
      float acc = 0.f;
      if (j < 100) {
        acc = linear_b[j];
        #pragma unroll
        for (int l = 0; l < 10; ++l) acc += za[l] * linear_W[l * 100 + j];
      }
      creg[jj] = acc;
      hT[j][sb] = acc;
    }
  }
  __syncthreads();

  // const_x = h0 @ Wx[0:100] + b (padded cols), kept in GEMM-role registers
  float cx[4][8];
  #pragma unroll
  for (int m = 0; m < 8; ++m) {
    float bp = BP[gj + 64 * m];
    cx[0][m] = bp; cx[1][m] = bp; cx[2][m] = bp; cx[3][m] = bp;
  }
  for (int k = 0; k < 100; k += 4) {
    #pragma unroll
    for (int kk = 0; kk < 4; ++kk) {
      float4 h4 = *(const float4*)(&hT[k + kk][bq * 4]);
      const float* wr = WX + (k + kk) * 512 + gj;
      #pragma unroll
      for (int m = 0; m < 8; ++m) {
        float w = wr[64 * m];
        cx[0][m] = fmaf(h4.x, w, cx[0][m]);
        cx[1][m] = fmaf(h4.y, w, cx[1][m]);
        cx[2][m] = fmaf(h4.z, w, cx[2][m]);
        cx[3][m] = fmaf(h4.w, w, cx[3][m]);
      }
    }
  }

  // scalar-chain state (used only by soct==0 threads)
  float des_v = 1.f, des_tg = 0.f, min_jx = 0.f, max_a = 1.f;
  float inv2s = 0.f, inv_dv = 1.f, ego_v = 0.f, ego_x = 0.f, act = 0.f, attb = 0.f;
  if (soct == 0) {
    const float* P = idm_params + bg_state * 5;
    des_v = P[0]; des_tg = P[1]; min_jx = P[2]; max_a = P[3];
    float min_a = P[4];
    inv2s = 0.5f / sqrtf(max_a * min_a);
    inv_dv = 1.f / des_v;
    ego_v = idm_s[(size_t)bg_state * T_STEPS * 8 + 0];
    ego_x = idm_s[(size_t)bg_state * T_STEPS * 8 + 3];
    attb = att_b[0];
  }

  for (int t = 0; t < T_STEPS; ++t) {
    // ---- GEMM role: z = cx + sdv terms + h @ Wh ----
    float z[4][8];
    {
      float s0[4], s1[4];
      #pragma unroll
      for (int bs = 0; bs < 4; ++bs) {
        const float* sp = sdv_acts + ((size_t)(b0 + bs) * T_STEPS + t) * 2;
        s0[bs] = sp[0]; s1[bs] = sp[1];
      }
      const float* w0 = WX + 100 * 512 + gj;
      const float* w1 = WX + 101 * 512 + gj;
      #pragma unroll
      for (int m = 0; m < 8; ++m) {
        float a = w0[64 * m], b = w1[64 * m];
        #pragma unroll
        for (int bs = 0; bs < 4; ++bs)
          z[bs][m] = cx[bs][m] + s0[bs] * a + s1[bs] * b;
      }
    }
    for (int k = 0; k < 100; k += 4) {
      #pragma unroll
      for (int kk = 0; kk < 4; ++kk) {
        float4 h4 = *(const float4*)(&hT[k + kk][bq * 4]);  // wave-uniform broadcast
        const float* wr = WH + (k + kk) * 512 + gj;
        #pragma unroll
        for (int m = 0; m < 8; ++m) {
          float w = wr[64 * m];
          z[0][m] = fmaf(h4.x, w, z[0][m]);
          z[1][m] = fmaf(h4.y, w, z[1][m]);
          z[2][m] = fmaf(h4.z, w, z[2][m]);
          z[3][m] = fmaf(h4.w, w, z[3][m]);
        }
      }
    }
    #pragma unroll
    for (int bs = 0; bs < 4; ++bs) {
      #pragma unroll
      for (int m = 0; m < 8; ++m)
        zS[bq * 4 + bs][gj + 64 * m] = z[bs][m];  // 2-way banks: free
    }
    __syncthreads();  // B1: all reads of old h done, z published

    // ---- state role: LSTM gates for own (sb, sj0..sj0+7) ----
    float zi[8], zf[8], zg[8], zo[8];
    *(float4*)&zi[0] = *(const float4*)(&zS[sb][0 * 128 + sj0]);
    *(float4*)&zi[4] = *(const float4*)(&zS[sb][0 * 128 + sj0 + 4]);
    *(float4*)&zf[0] = *(const float4*)(&zS[sb][1 * 128 + sj0]);
    *(float4*)&zf[4] = *(const float4*)(&zS[sb][1 * 128 + sj0 + 4]);
    *(float4*)&zg[0] = *(const float4*)(&zS[sb][2 * 128 + sj0]);
    *(float4*)&zg[4] = *(const float4*)(&zS[sb][2 * 128 + sj0 + 4]);
    *(float4*)&zo[0] = *(const float4*)(&zS[sb][3 * 128 + sj0]);
    *(float4*)&zo[4] = *(const float4*)(&zS[sb][3 * 128 + sj0 + 4]);
    float attp = 0.f;
    #pragma unroll
    for (int jj = 0; jj < 8; ++jj) {
      float cc = sigf(zf[jj]) * creg[jj] + sigf(zi[jj]) * tanhf_(zg[jj]);
      float hh = sigf(zo[jj]) * tanhf_(cc);
      creg[jj] = cc;
      hT[sj0 + jj][sb] = hh;
      attp += hh * AW[sj0 + jj];  // AW=0 for j>=100
    }
    part[sb][soct] = attp;
    __syncthreads();  // B2: new h + partials published

    // ---- per-batch scalar chain ----
    if (soct == 0) {
      ego_v += act * 0.1f;
      ego_x += ego_v * 0.1f + act * 0.005f;
      const float* s = idm_s + ((size_t)bg_state * T_STEPS + t) * 8;
      float f_v = s[1], m_v = s[2], f_x = s[4], m_x = s[5], f_ex = s[6], m_ex = s[7];
      float af, am;
      {
        float dx = fminf(fmaxf(f_x - ego_x, 0.5f), 1000.f);
        float dg = min_jx + fmaxf(0.f, des_tg * ego_v + ego_v * (ego_v - f_v) * inv2s);
        float r = ego_v * inv_dv; float r2 = r * r; float q = dg / dx;
        af = fminf(fmaxf(max_a * (1.f - r2 * r2 - q * q), -3.f), 3.f);
      }
      {
        float dx = fminf(fmaxf(m_x - ego_x, 0.5f), 1000.f);
        float dg = min_jx + fmaxf(0.f, des_tg * ego_v + ego_v * (ego_v - m_v) * inv2s);
        float r = ego_v * inv_dv; float r2 = r * r; float q = dg / dx;
        am = fminf(fmaxf(max_a * (1.f - r2 * r2 - q * q), -3.f), 3.f);
      }
      float nf = noise_f[(size_t)t * B_TOT + bg_state];
      float nm = noise_m[(size_t)t * B_TOT + bg_state];
      float ef = f_ex * af + (1.f - f_ex) * nf;
      float em = m_ex * am + (1.f - m_ex) * nm;
      float lg = attb;
      #pragma unroll
      for (int q2 = 0; q2 < 16; ++q2) lg += part[sb][q2];
      float att = sigf(5.f * lg);
      act = (1.f - att) * ef + att * em;
      out[(size_t)bg_state * T_STEPS + t] = act;
      out[(size_t)B_TOT * T_STEPS + (size_t)bg_state * T_STEPS + t] = att;
    }
  }
}

extern "C" void kernel_launch(void* const* d_in, const int* in_sizes, int n_in,
                              void* d_out, int out_size, void* d_ws, size_t ws_size,
                              hipStream_t stream) {
  const float* z_att      = (const float*)d_in[0];
  // d_in[1] enc_h: unused by the reference
  const float* idm_params = (const float*)d_in[2];
  const float* idm_s      = (const float*)d_in[3];
  const float* sdv_acts   = (const float*)d_in[4];
  const float* linear_W   = (const float*)d_in[5];
  const float* linear_b   = (const float*)d_in[6];
  const float* lstm_Wx    = (const float*)d_in[7];
  const float* lstm_Wh    = (const float*)d_in[8];
  const float* lstm_b     = (const float*)d_in[9];
  const float* att_W      = (const float*)d_in[10];
  const float* att_b      = (const float*)d_in[11];
  const float* noise_f    = (const float*)d_in[12];
  const float* noise_m    = (const float*)d_in[13];
  float* out = (float*)d_out;
  float* ws  = (float*)d_ws;

  idm_prep<<<204, 256, 0, stream>>>(lstm_Wx, lstm_Wh, lstm_b, att_W, ws);
  idm_main<<<B_TOT / NB, 256, 0, stream>>>(z_att, idm_params, idm_s, sdv_acts,
                                           linear_W, linear_b, att_b,
                                           noise_f, noise_m, ws, out);
}

// Round 2
// 260.747 us; speedup vs baseline: 4.4630x; 4.4630x over previous
//
#include <hip/hip_runtime.h>
#include <math.h>

// IDMForwardSim R2: MFMA-f16 LSTM GEMM. B=8192, T=40, H=100 (pad 128), K=100+2(sdv)->128.
// Prep packs Wh/Wx into B-frag order (f16) in ws; main kernel holds them in 128 VGPRs.
// 512 blocks x 256 thr, NB=16 batches/block. Wave w owns N-tiles {w+4i}: all 4 gates of a
// (batch,j) land in the same lane (C-layout col=l&15,row=quad*4+r) -> lane-local gates,
// c-state in regs. h round-trips LDS (A-layout reads). Scalar IDM chain unchanged from R1.

#define B_TOT 8192
#define T_STEPS 40
#define NB 16

typedef _Float16 f16;
typedef f16 f16x8 __attribute__((ext_vector_type(8)));
typedef float f32x4 __attribute__((ext_vector_type(4)));

__device__ __forceinline__ float sigf(float x) { return 1.f / (1.f + __expf(-x)); }
__device__ __forceinline__ float tanhf_(float x) {
  float xc = fminf(fmaxf(x, -15.f), 15.f);
  float e = __expf(2.f * xc);
  return (e - 1.f) / (e + 1.f);
}

// ws layout: whb f16[65536] | wxb f16[65536] | bp f32[512] | aw f32[128]
// B-frag order: elem((tile*4+kf)*64 + lane)*8 + j  == Wpad[k = kf*32+(lane>>4)*8+j][n = tile*16+(lane&15)]

__global__ __launch_bounds__(256) void idm_prep(
    const float* __restrict__ Wx, const float* __restrict__ Wh,
    const float* __restrict__ bvec, const float* __restrict__ attw,
    f16* __restrict__ whb, f16* __restrict__ wxb,
    float* __restrict__ bp, float* __restrict__ aw)
{
  int i = blockIdx.x * 256 + threadIdx.x;  // 0..65535
  int j    = i & 7;
  int l    = (i >> 3) & 63;
  int kf   = (i >> 9) & 3;
  int tile = i >> 11;
  int k = kf * 32 + ((l >> 4) & 3) * 8 + j;
  int n = tile * 16 + (l & 15);
  int g = n >> 7, j128 = n & 127;
  int col = g * 100 + j128;
  float vh = 0.f, vx = 0.f;
  if (j128 < 100) {
    if (k < 100)      { vh = Wh[k * 400 + col]; vx = Wx[k * 400 + col]; }
    else if (k < 102) { vh = Wx[k * 400 + col]; }  // sdv rows folded into Wh-pad
  }
  whb[i] = (f16)vh;
  wxb[i] = (f16)vx;
  if (i < 512) { int gg = i >> 7, jj = i & 127; bp[i] = (jj < 100) ? bvec[gg * 100 + jj] : 0.f; }
  if (i < 128) aw[i] = (i < 100) ? attw[i] : 0.f;
}

__global__ __launch_bounds__(256, 2) void idm_main(
    const float* __restrict__ z_att,
    const float* __restrict__ idm_params,
    const float* __restrict__ idm_s,
    const float* __restrict__ sdv_acts,
    const float* __restrict__ linear_W,
    const float* __restrict__ linear_b,
    const float* __restrict__ att_b,
    const float* __restrict__ noise_f,
    const float* __restrict__ noise_m,
    const f16* __restrict__ whb, const f16* __restrict__ wxb,
    const float* __restrict__ bp, const float* __restrict__ aw,
    float* __restrict__ out)
{
  __shared__ f16 hS[16][136];   // [batch][k], k: 0..99=h, 100..101=sdv_t, 102..135=0/pad
  __shared__ float part[16][4]; // att partials per wave

  const int tid = threadIdx.x;
  const int w  = tid >> 6;   // wave 0..3
  const int l  = tid & 63;
  const int lr = l & 15;     // A-row / C-col lane component
  const int lq = l >> 4;     // quad
  const int b0g = blockIdx.x * NB;

  // zero hS (incl. pad cols) so dead K-rows are exact 0, never NaN
  {
    unsigned* p = (unsigned*)&hS[0][0];
    for (int idx = tid; idx < 1088; idx += 256) p[idx] = 0u;
  }
  __syncthreads();

  // Phase A: h0 = att_proj (f16 into hS), sdv_0 rows
  {
    int b = tid >> 4, oct = tid & 15;
    float za[10];
    #pragma unroll
    for (int t2 = 0; t2 < 10; ++t2) za[t2] = z_att[(b0g + b) * 10 + t2];
    #pragma unroll
    for (int jj = 0; jj < 8; ++jj) {
      int j = oct * 8 + jj;
      float acc = 0.f;
      if (j < 100) {
        acc = linear_b[j];
        #pragma unroll
        for (int t2 = 0; t2 < 10; ++t2) acc = fmaf(za[t2], linear_W[t2 * 100 + j], acc);
      }
      if (j < 128) hS[b][j] = (f16)acc;
    }
    if (tid < 32) {
      int bb = tid >> 1, ii = tid & 1;
      hS[bb][100 + ii] = (f16)sdv_acts[((size_t)(b0g + bb) * T_STEPS + 0) * 2 + ii];
    }
  }
  __syncthreads();

  // cx = bias + h0 @ Wx  (MFMA with Wx B-frags; rows 100..127 of WxB are 0)
  f16x8 wb[8][4];
  #pragma unroll
  for (int i = 0; i < 8; ++i) {
    int tile = w + 4 * i;
    #pragma unroll
    for (int kf = 0; kf < 4; ++kf)
      wb[i][kf] = *(const f16x8*)(wxb + ((size_t)(tile * 4 + kf) * 64 + l) * 8);
  }
  f32x4 cx[8];
  {
    f16x8 a0 = *(const f16x8*)(&hS[lr][0  + lq * 8]);
    f16x8 a1 = *(const f16x8*)(&hS[lr][32 + lq * 8]);
    f16x8 a2 = *(const f16x8*)(&hS[lr][64 + lq * 8]);
    f16x8 a3 = *(const f16x8*)(&hS[lr][96 + lq * 8]);
    #pragma unroll
    for (int i = 0; i < 8; ++i) {
      int tile = w + 4 * i;
      float bpv = bp[tile * 16 + lr];
      f32x4 c = {bpv, bpv, bpv, bpv};
      c = __builtin_amdgcn_mfma_f32_16x16x32_f16(a0, wb[i][0], c, 0, 0, 0);
      c = __builtin_amdgcn_mfma_f32_16x16x32_f16(a1, wb[i][1], c, 0, 0, 0);
      c = __builtin_amdgcn_mfma_f32_16x16x32_f16(a2, wb[i][2], c, 0, 0, 0);
      c = __builtin_amdgcn_mfma_f32_16x16x32_f16(a3, wb[i][3], c, 0, 0, 0);
      cx[i] = c;
    }
  }
  // reload wb with Wh B-frags (loop-invariant, lives in VGPRs)
  #pragma unroll
  for (int i = 0; i < 8; ++i) {
    int tile = w + 4 * i;
    #pragma unroll
    for (int kf = 0; kf < 4; ++kf)
      wb[i][kf] = *(const f16x8*)(whb + ((size_t)(tile * 4 + kf) * 64 + l) * 8);
  }

  // lane-local LSTM state: chunks q=0,1 -> j0 = 16*(w+4q)+lr; batches lq*4+r
  const int j0a = 16 * w + lr;
  const int j0b = 16 * (w + 4) + lr;
  float aw2[2] = {aw[j0a], aw[j0b]};
  float cst[2][4];
  #pragma unroll
  for (int r = 0; r < 4; ++r) {
    cst[0][r] = (float)hS[lq * 4 + r][j0a];
    cst[1][r] = (float)hS[lq * 4 + r][j0b];
  }
  const bool q1live = (w != 3);  // wave 3 chunk 1 = j 112..127, all pad

  // scalar-chain state (tid<16 -> batch tid)
  float des_tg = 0.f, min_jx = 0.f, max_a = 1.f, inv2s = 0.f, inv_dv = 1.f;
  float ego_v = 0.f, ego_x = 0.f, act = 0.f, attb = 0.f;
  if (tid < 16) {
    const float* P = idm_params + (size_t)(b0g + tid) * 5;
    float des_v = P[0]; des_tg = P[1]; min_jx = P[2]; max_a = P[3];
    inv2s = 0.5f / sqrtf(max_a * P[4]);
    inv_dv = 1.f / des_v;
    ego_v = idm_s[(size_t)(b0g + tid) * T_STEPS * 8 + 0];
    ego_x = idm_s[(size_t)(b0g + tid) * T_STEPS * 8 + 3];
    attb = att_b[0];
  }

  for (int t = 0; t < T_STEPS; ++t) {
    // A-frags: h_{t-1} + sdv_t
    f16x8 a0 = *(const f16x8*)(&hS[lr][0  + lq * 8]);
    f16x8 a1 = *(const f16x8*)(&hS[lr][32 + lq * 8]);
    f16x8 a2 = *(const f16x8*)(&hS[lr][64 + lq * 8]);
    f16x8 a3 = *(const f16x8*)(&hS[lr][96 + lq * 8]);
    f32x4 z[8];
    #pragma unroll
    for (int i = 0; i < 8; ++i) {
      if ((i & 1) && !q1live) continue;  // wave-uniform skip of dead tiles
      f32x4 c = cx[i];
      c = __builtin_amdgcn_mfma_f32_16x16x32_f16(a0, wb[i][0], c, 0, 0, 0);
      c = __builtin_amdgcn_mfma_f32_16x16x32_f16(a1, wb[i][1], c, 0, 0, 0);
      c = __builtin_amdgcn_mfma_f32_16x16x32_f16(a2, wb[i][2], c, 0, 0, 0);
      c = __builtin_amdgcn_mfma_f32_16x16x32_f16(a3, wb[i][3], c, 0, 0, 0);
      z[i] = c;
    }
    // gates: lane-local (tile i = q + 2g)
    float hnew[2][4];
    float attp[4] = {0.f, 0.f, 0.f, 0.f};
    #pragma unroll
    for (int q = 0; q < 2; ++q) {
      if (q == 1 && !q1live) continue;
      #pragma unroll
      for (int r = 0; r < 4; ++r) {
        float zi_ = z[q + 0][r];
        float zf_ = z[q + 2][r];
        float zg_ = z[q + 4][r];
        float zo_ = z[q + 6][r];
        float cc = sigf(zf_) * cst[q][r] + sigf(zi_) * tanhf_(zg_);
        float hh = sigf(zo_) * tanhf_(cc);
        cst[q][r] = cc;
        hnew[q][r] = hh;
        attp[r] = fmaf(hh, aw2[q], attp[r]);
      }
    }
    // butterfly over col-lanes (bits 0..3): same-batch partials
    #pragma unroll
    for (int m = 1; m < 16; m <<= 1) {
      #pragma unroll
      for (int r = 0; r < 4; ++r) attp[r] += __shfl_xor(attp[r], m, 64);
    }
    __syncthreads();  // B1: all A-frag reads complete
    #pragma unroll
    for (int q = 0; q < 2; ++q) {
      if (q == 1 && !q1live) continue;
      int jj = (q == 0) ? j0a : j0b;
      #pragma unroll
      for (int r = 0; r < 4; ++r) hS[lq * 4 + r][jj] = (f16)hnew[q][r];
    }
    if (lr == 0) {
      #pragma unroll
      for (int r = 0; r < 4; ++r) part[lq * 4 + r][w] = attp[r];
    }
    if (t + 1 < T_STEPS && tid < 32) {
      int bb = tid >> 1, ii = tid & 1;
      hS[bb][100 + ii] = (f16)sdv_acts[((size_t)(b0g + bb) * T_STEPS + (t + 1)) * 2 + ii];
    }
    __syncthreads();  // B2: h_t / part / sdv_{t+1} visible

    if (tid < 16) {
      int bg = b0g + tid;
      ego_v += act * 0.1f;
      ego_x += ego_v * 0.1f + act * 0.005f;
      const float* s = idm_s + ((size_t)bg * T_STEPS + t) * 8;
      float f_v = s[1], m_v = s[2], f_x = s[4], m_x = s[5], f_ex = s[6], m_ex = s[7];
      float af_, am_;
      {
        float dx = fminf(fmaxf(f_x - ego_x, 0.5f), 1000.f);
        float dg = min_jx + fmaxf(0.f, des_tg * ego_v + ego_v * (ego_v - f_v) * inv2s);
        float r = ego_v * inv_dv; float r2 = r * r; float q = dg / dx;
        af_ = fminf(fmaxf(max_a * (1.f - r2 * r2 - q * q), -3.f), 3.f);
      }
      {
        float dx = fminf(fmaxf(m_x - ego_x, 0.5f), 1000.f);
        float dg = min_jx + fmaxf(0.f, des_tg * ego_v + ego_v * (ego_v - m_v) * inv2s);
        float r = ego_v * inv_dv; float r2 = r * r; float q = dg / dx;
        am_ = fminf(fmaxf(max_a * (1.f - r2 * r2 - q * q), -3.f), 3.f);
      }
      float nf = noise_f[(size_t)t * B_TOT + bg];
      float nm = noise_m[(size_t)t * B_TOT + bg];
      float ef = f_ex * af_ + (1.f - f_ex) * nf;
      float em = m_ex * am_ + (1.f - m_ex) * nm;
      float lg = attb + part[tid][0] + part[tid][1] + part[tid][2] + part[tid][3];
      float att = sigf(5.f * lg);
      act = (1.f - att) * ef + att * em;
      out[(size_t)bg * T_STEPS + t] = act;
      out[(size_t)B_TOT * T_STEPS + (size_t)bg * T_STEPS + t] = att;
    }
  }
}

extern "C" void kernel_launch(void* const* d_in, const int* in_sizes, int n_in,
                              void* d_out, int out_size, void* d_ws, size_t ws_size,
                              hipStream_t stream) {
  const float* z_att      = (const float*)d_in[0];
  const float* idm_params = (const float*)d_in[2];
  const float* idm_s      = (const float*)d_in[3];
  const float* sdv_acts   = (const float*)d_in[4];
  const float* linear_W   = (const float*)d_in[5];
  const float* linear_b   = (const float*)d_in[6];
  const float* lstm_Wx    = (const float*)d_in[7];
  const float* lstm_Wh    = (const float*)d_in[8];
  const float* lstm_b     = (const float*)d_in[9];
  const float* att_W      = (const float*)d_in[10];
  const float* att_b      = (const float*)d_in[11];
  const float* noise_f    = (const float*)d_in[12];
  const float* noise_m    = (const float*)d_in[13];
  float* out = (float*)d_out;

  f16*   whb = (f16*)d_ws;
  f16*   wxb = whb + 65536;
  float* bp  = (float*)((char*)d_ws + 262144);
  float* aw  = bp + 512;

  idm_prep<<<256, 256, 0, stream>>>(lstm_Wx, lstm_Wh, lstm_b, att_W, whb, wxb, bp, aw);
  idm_main<<<B_TOT / NB, 256, 0, stream>>>(z_att, idm_params, idm_s, sdv_acts,
                                           linear_W, linear_b, att_b,
                                           noise_f, noise_m, whb, wxb, bp, aw, out);
}

// Round 3
// 228.975 us; speedup vs baseline: 5.0823x; 1.1388x over previous
//
#include <hip/hip_runtime.h>
#include <math.h>

// IDMForwardSim R3: occupancy + short-path restructure.
// 512 blocks x 448 thr (7 waves), NB=16. Wave w owns j-tile w: N-tiles {w,w+8,w+16,w+24}
// = the 4 gates of j=16w+lr -> 4 gate-elements/lane, weights 64 VGPR/wave.
// launch_bounds(448,4) -> 2 blocks/CU = 14 waves/CU. Double-buffered hS/part -> 1 barrier
// per step. rcp-based gates (no v_div sequences). Scalar-chain loads issued pre-barrier.

#define B_TOT 8192
#define T_STEPS 40
#define NB 16

typedef _Float16 f16;
typedef f16 f16x8 __attribute__((ext_vector_type(8)));
typedef float f32x4 __attribute__((ext_vector_type(4)));

__device__ __forceinline__ float rcpf(float x) { return __builtin_amdgcn_rcpf(x); }

// ws layout: whb f16[65536] | wxb f16[65536] | bp f32[512] | aw f32[128]
// B-frag order: elem((tile*4+kf)*64 + lane)*8 + j == Wpad[k=kf*32+(lane>>4)*8+j][n=tile*16+(lane&15)]

__global__ __launch_bounds__(256) void idm_prep(
    const float* __restrict__ Wx, const float* __restrict__ Wh,
    const float* __restrict__ bvec, const float* __restrict__ attw,
    f16* __restrict__ whb, f16* __restrict__ wxb,
    float* __restrict__ bp, float* __restrict__ aw)
{
  int i = blockIdx.x * 256 + threadIdx.x;  // 0..65535
  int j    = i & 7;
  int l    = (i >> 3) & 63;
  int kf   = (i >> 9) & 3;
  int tile = i >> 11;
  int k = kf * 32 + ((l >> 4) & 3) * 8 + j;
  int n = tile * 16 + (l & 15);
  int g = n >> 7, j128 = n & 127;
  int col = g * 100 + j128;
  float vh = 0.f, vx = 0.f;
  if (j128 < 100) {
    if (k < 100)      { vh = Wh[k * 400 + col]; vx = Wx[k * 400 + col]; }
    else if (k < 102) { vh = Wx[k * 400 + col]; }  // sdv rows folded into Wh-pad
  }
  whb[i] = (f16)vh;
  wxb[i] = (f16)vx;
  if (i < 512) { int gg = i >> 7, jj = i & 127; bp[i] = (jj < 100) ? bvec[gg * 100 + jj] : 0.f; }
  if (i < 128) aw[i] = (i < 100) ? attw[i] : 0.f;
}

__global__ __launch_bounds__(448, 4) void idm_main(
    const float* __restrict__ z_att,
    const float* __restrict__ idm_params,
    const float* __restrict__ idm_s,
    const float* __restrict__ sdv_acts,
    const float* __restrict__ linear_W,
    const float* __restrict__ linear_b,
    const float* __restrict__ att_b,
    const float* __restrict__ noise_f,
    const float* __restrict__ noise_m,
    const f16* __restrict__ whb, const f16* __restrict__ wxb,
    const float* __restrict__ bp, const float* __restrict__ aw,
    float* __restrict__ out)
{
  __shared__ f16 hS[2][16][136];    // [buf][batch][k] k:0..99 h, 100..101 sdv, 102..135 zero
  __shared__ float part[2][16][8];  // [buf][batch][wave] att partials

  const int tid = threadIdx.x;
  const int w  = tid >> 6;   // 0..6 (j-tile)
  const int l  = tid & 63;
  const int lr = l & 15;
  const int lq = l >> 4;
  const int b0g = blockIdx.x * NB;
  const int jcol = 16 * w + lr;   // this lane's j (0..111)

  // zero both hS buffers (pad rows must be exact 0)
  for (int idx = tid; idx < 2176; idx += 448) ((unsigned*)hS)[idx] = 0u;
  __syncthreads();

  // Phase A: h0 = att_proj into hS[0] (j<100), sdv_0 rows
  if (tid < 256) {
    int b = tid >> 4, oct = tid & 15;
    float za[10];
    #pragma unroll
    for (int t2 = 0; t2 < 10; ++t2) za[t2] = z_att[(b0g + b) * 10 + t2];
    #pragma unroll
    for (int jj = 0; jj < 8; ++jj) {
      int j = oct * 8 + jj;
      if (j < 100) {
        float acc = linear_b[j];
        #pragma unroll
        for (int t2 = 0; t2 < 10; ++t2) acc = fmaf(za[t2], linear_W[t2 * 100 + j], acc);
        hS[0][b][j] = (f16)acc;
      }
    }
  }
  if (tid < 32) {
    int bb = tid >> 1, ii = tid & 1;
    hS[0][bb][100 + ii] = (f16)sdv_acts[((size_t)(b0g + bb) * T_STEPS + 0) * 2 + ii];
  }
  __syncthreads();

  // weight fragments: first Wx (for cx), then Wh (loop-invariant)
  f16x8 wb[4][4];
  #pragma unroll
  for (int g = 0; g < 4; ++g) {
    int tile = w + 8 * g;
    #pragma unroll
    for (int kf = 0; kf < 4; ++kf)
      wb[g][kf] = *(const f16x8*)(wxb + ((size_t)(tile * 4 + kf) * 64 + l) * 8);
  }
  f32x4 cx[4];
  #pragma unroll
  for (int g = 0; g < 4; ++g) {
    float bpv = bp[(w + 8 * g) * 16 + lr];
    f32x4 c = {bpv, bpv, bpv, bpv};
    cx[g] = c;
  }
  #pragma unroll
  for (int kf = 0; kf < 4; ++kf) {
    f16x8 a = *(const f16x8*)(&hS[0][lr][kf * 32 + lq * 8]);
    #pragma unroll
    for (int g = 0; g < 4; ++g)
      cx[g] = __builtin_amdgcn_mfma_f32_16x16x32_f16(a, wb[g][kf], cx[g], 0, 0, 0);
  }
  #pragma unroll
  for (int g = 0; g < 4; ++g) {
    int tile = w + 8 * g;
    #pragma unroll
    for (int kf = 0; kf < 4; ++kf)
      wb[g][kf] = *(const f16x8*)(whb + ((size_t)(tile * 4 + kf) * 64 + l) * 8);
  }

  // lane-local LSTM state: 4 batches (lq*4+r), one j (jcol)
  const float aw1 = aw[jcol];
  float cst[4];
  #pragma unroll
  for (int r = 0; r < 4; ++r) cst[r] = (float)hS[0][lq * 4 + r][jcol];

  // scalar-chain persistent state (tid<16 -> batch tid)
  float des_tg = 0.f, min_jx = 0.f, max_a = 1.f, inv2s = 0.f, inv_dv = 1.f;
  float ego_v = 0.f, ego_x = 0.f, act = 0.f, attb = 0.f;
  if (tid < 16) {
    const float* P = idm_params + (size_t)(b0g + tid) * 5;
    float des_v = P[0]; des_tg = P[1]; min_jx = P[2]; max_a = P[3];
    inv2s = 0.5f / sqrtf(max_a * P[4]);
    inv_dv = rcpf(des_v);
    ego_v = idm_s[(size_t)(b0g + tid) * T_STEPS * 8 + 0];
    ego_x = idm_s[(size_t)(b0g + tid) * T_STEPS * 8 + 3];
    attb = att_b[0];
  }

  int p = 0;
  for (int t = 0; t < T_STEPS; ++t) {
    // early scalar-chain loads (overlap with GEMM below)
    float4 s03 = {0,0,0,0}, s47 = {0,0,0,0};
    float nf = 0.f, nm = 0.f;
    if (tid < 16) {
      const float* s = idm_s + ((size_t)(b0g + tid) * T_STEPS + t) * 8;
      s03 = *(const float4*)(s);
      s47 = *(const float4*)(s + 4);
      nf = noise_f[(size_t)t * B_TOT + b0g + tid];
      nm = noise_m[(size_t)t * B_TOT + b0g + tid];
    }

    // z = cx + [h_{t-1}, sdv_t] @ Whb   (kf-outer: one live A-frag)
    f32x4 z0 = cx[0], z1 = cx[1], z2 = cx[2], z3 = cx[3];
    #pragma unroll
    for (int kf = 0; kf < 4; ++kf) {
      f16x8 a = *(const f16x8*)(&hS[p][lr][kf * 32 + lq * 8]);
      z0 = __builtin_amdgcn_mfma_f32_16x16x32_f16(a, wb[0][kf], z0, 0, 0, 0);
      z1 = __builtin_amdgcn_mfma_f32_16x16x32_f16(a, wb[1][kf], z1, 0, 0, 0);
      z2 = __builtin_amdgcn_mfma_f32_16x16x32_f16(a, wb[2][kf], z2, 0, 0, 0);
      z3 = __builtin_amdgcn_mfma_f32_16x16x32_f16(a, wb[3][kf], z3, 0, 0, 0);
    }

    // gates: 4 elements/lane (batch=lq*4+r, j=jcol); 5 exp + 3 rcp each
    float hnew[4], attp[4];
    #pragma unroll
    for (int r = 0; r < 4; ++r) {
      float zi_ = z0[r], zf_ = z1[r], zg_ = z2[r], zo_ = z3[r];
      float ef = __expf(-fmaxf(zf_, -44.f));
      float sf = rcpf(1.f + ef);
      float ea = __expf(-fmaxf(zi_, -44.f));
      float eb = __expf(-2.f * fminf(fmaxf(zg_, -15.f), 15.f));
      float it = (1.f - eb) * rcpf((1.f + ea) * (1.f + eb));
      float cc = fmaf(sf, cst[r], it);
      float eo = __expf(-fmaxf(zo_, -44.f));
      float ec = __expf(-2.f * fminf(fmaxf(cc, -15.f), 15.f));
      float hh = (1.f - ec) * rcpf((1.f + eo) * (1.f + ec));
      cst[r] = cc;
      hnew[r] = hh;
      attp[r] = hh * aw1;   // aw1=0 for j>=100
    }
    // reduce attp over lr lanes (bits 0..3)
    #pragma unroll
    for (int m = 1; m < 16; m <<= 1) {
      #pragma unroll
      for (int r = 0; r < 4; ++r) attp[r] += __shfl_xor(attp[r], m, 64);
    }

    // publish h_t, partials, sdv_{t+1} into buffer p^1 (no conflicts: j<100 mask)
    if (jcol < 100) {
      #pragma unroll
      for (int r = 0; r < 4; ++r) hS[p ^ 1][lq * 4 + r][jcol] = (f16)hnew[r];
    }
    if (lr == 0) {
      #pragma unroll
      for (int r = 0; r < 4; ++r) part[t & 1][lq * 4 + r][w] = attp[r];
    }
    if (t + 1 < T_STEPS && tid < 32) {
      int bb = tid >> 1, ii = tid & 1;
      hS[p ^ 1][bb][100 + ii] = (f16)sdv_acts[((size_t)(b0g + bb) * T_STEPS + (t + 1)) * 2 + ii];
    }
    __syncthreads();  // single barrier per step

    // per-batch scalar chain (off critical path until next barrier)
    if (tid < 16) {
      int bg = b0g + tid;
      ego_v += act * 0.1f;
      ego_x += ego_v * 0.1f + act * 0.005f;
      float f_v = s03.y, m_v = s03.z, f_x = s47.x, m_x = s47.y, f_ex = s47.z, m_ex = s47.w;
      float af_, am_;
      {
        float dx = fminf(fmaxf(f_x - ego_x, 0.5f), 1000.f);
        float dg = min_jx + fmaxf(0.f, des_tg * ego_v + ego_v * (ego_v - f_v) * inv2s);
        float r = ego_v * inv_dv; float r2 = r * r; float q = dg * rcpf(dx);
        af_ = fminf(fmaxf(max_a * (1.f - r2 * r2 - q * q), -3.f), 3.f);
      }
      {
        float dx = fminf(fmaxf(m_x - ego_x, 0.5f), 1000.f);
        float dg = min_jx + fmaxf(0.f, des_tg * ego_v + ego_v * (ego_v - m_v) * inv2s);
        float r = ego_v * inv_dv; float r2 = r * r; float q = dg * rcpf(dx);
        am_ = fminf(fmaxf(max_a * (1.f - r2 * r2 - q * q), -3.f), 3.f);
      }
      float ef2 = f_ex * af_ + (1.f - f_ex) * nf;
      float em2 = m_ex * am_ + (1.f - m_ex) * nm;
      float lg = attb;
      #pragma unroll
      for (int q2 = 0; q2 < 7; ++q2) lg += part[t & 1][tid][q2];
      float eatt = __expf(-fmaxf(5.f * lg, -44.f));
      float att = rcpf(1.f + eatt);
      act = (1.f - att) * ef2 + att * em2;
      out[(size_t)bg * T_STEPS + t] = act;
      out[(size_t)B_TOT * T_STEPS + (size_t)bg * T_STEPS + t] = att;
    }
    p ^= 1;
  }
}

extern "C" void kernel_launch(void* const* d_in, const int* in_sizes, int n_in,
                              void* d_out, int out_size, void* d_ws, size_t ws_size,
                              hipStream_t stream) {
  const float* z_att      = (const float*)d_in[0];
  const float* idm_params = (const float*)d_in[2];
  const float* idm_s      = (const float*)d_in[3];
  const float* sdv_acts   = (const float*)d_in[4];
  const float* linear_W   = (const float*)d_in[5];
  const float* linear_b   = (const float*)d_in[6];
  const float* lstm_Wx    = (const float*)d_in[7];
  const float* lstm_Wh    = (const float*)d_in[8];
  const float* lstm_b     = (const float*)d_in[9];
  const float* att_W      = (const float*)d_in[10];
  const float* att_b      = (const float*)d_in[11];
  const float* noise_f    = (const float*)d_in[12];
  const float* noise_m    = (const float*)d_in[13];
  float* out = (float*)d_out;

  f16*   whb = (f16*)d_ws;
  f16*   wxb = whb + 65536;
  float* bp  = (float*)((char*)d_ws + 262144);
  float* aw  = bp + 512;

  idm_prep<<<256, 256, 0, stream>>>(lstm_Wx, lstm_Wh, lstm_b, att_W, whb, wxb, bp, aw);
  idm_main<<<B_TOT / NB, 448, 0, stream>>>(z_att, idm_params, idm_s, sdv_acts,
                                           linear_W, linear_b, att_b,
                                           noise_f, noise_m, whb, wxb, bp, aw, out);
}

// Round 4
// 220.024 us; speedup vs baseline: 5.2890x; 1.0407x over previous
//
#include <hip/hip_runtime.h>
#include <math.h>

// IDMForwardSim R4: decoupled recurrence + scalar chain.
// idm_main: 512 blocks x 448 thr, per step only MFMA(z)+gates+h-exchange; writes
//   per-(b,t) attention-logit sums (f32) to global Pp (pipelined wave-0 fold).
// idm_scalar: 8192 threads replay ego/IDM/noise chain per batch, write both outputs.
// sdv staged to LDS once per block; no per-step global loads in the main loop.

#define B_TOT 8192
#define T_STEPS 40
#define NB 16

typedef _Float16 f16;
typedef f16 f16x8 __attribute__((ext_vector_type(8)));
typedef float f32x4 __attribute__((ext_vector_type(4)));

__device__ __forceinline__ float rcpf(float x) { return __builtin_amdgcn_rcpf(x); }

// ws layout (bytes): whb f16[65536] @0 | wxb f16[65536] @131072 | bp f32[512] @262144
//                    | aw f32[128] @264192 | Pp f32[40][8192] @294912

__global__ __launch_bounds__(256) void idm_prep(
    const float* __restrict__ Wx, const float* __restrict__ Wh,
    const float* __restrict__ bvec, const float* __restrict__ attw,
    f16* __restrict__ whb, f16* __restrict__ wxb,
    float* __restrict__ bp, float* __restrict__ aw)
{
  int i = blockIdx.x * 256 + threadIdx.x;  // 0..65535, i = k*512 + n (coalesced reads)
  int k = i >> 9, n = i & 511;
  int g = n >> 7, j128 = n & 127;
  float vh = 0.f, vx = 0.f;
  if (j128 < 100) {
    int col = g * 100 + j128;
    if (k < 100)      { vh = Wh[k * 400 + col]; vx = Wx[k * 400 + col]; }
    else if (k < 102) { vh = Wx[k * 400 + col]; }  // sdv rows folded into Wh-pad
  }
  // dest B-frag index: tile=n>>4, kf=k>>5, l=((k>>3)&3)*16+(n&15), j=k&7
  int idx = (((n >> 4) * 4 + (k >> 5)) * 64 + (((k >> 3) & 3) * 16 + (n & 15))) * 8 + (k & 7);
  whb[idx] = (f16)vh;
  wxb[idx] = (f16)vx;
  if (i < 512) { int gg = i >> 7, jj = i & 127; bp[i] = (jj < 100) ? bvec[gg * 100 + jj] : 0.f; }
  if (i < 128) aw[i] = (i < 100) ? attw[i] : 0.f;
}

__global__ __launch_bounds__(448, 4) void idm_main(
    const float* __restrict__ z_att,
    const float* __restrict__ linear_W,
    const float* __restrict__ linear_b,
    const float* __restrict__ sdv_acts,
    const f16* __restrict__ whb, const f16* __restrict__ wxb,
    const float* __restrict__ bp, const float* __restrict__ aw,
    float* __restrict__ Pp)
{
  __shared__ f16 hS[2][16][136];     // [buf][batch][k] 0..99 h, 100..101 sdv, 102..135 zero
  __shared__ f16 sdvS[T_STEPS][16][2];
  __shared__ float part[2][16][8];   // [buf][batch][wave(+pad slot7=0)]

  const int tid = threadIdx.x;
  const int w  = tid >> 6;   // 0..6 j-tile
  const int l  = tid & 63;
  const int lr = l & 15;
  const int lq = l >> 4;
  const int b0g = blockIdx.x * NB;
  const int jcol = 16 * w + lr;

  // zero hS (pad rows must stay exact 0) and part (slot 7 stays 0 forever)
  for (int idx = tid; idx < 2176; idx += 448) ((unsigned*)hS)[idx] = 0u;
  for (int idx = tid; idx < 256; idx += 448) ((float*)part)[idx] = 0.f;
  // stage sdv for all 40 steps (coalesced: 1280 consecutive floats)
  for (int idx = tid; idx < 1280; idx += 448) {
    float v = sdv_acts[(size_t)b0g * 80 + idx];
    int b = idx / 80, r = idx - b * 80;
    sdvS[r >> 1][b][r & 1] = (f16)v;
  }
  __syncthreads();

  // h0 = att_proj into hS[0]
  if (tid < 256) {
    int b = tid >> 4, oct = tid & 15;
    float za[10];
    #pragma unroll
    for (int t2 = 0; t2 < 10; ++t2) za[t2] = z_att[(b0g + b) * 10 + t2];
    #pragma unroll
    for (int jj = 0; jj < 8; ++jj) {
      int j = oct * 8 + jj;
      if (j < 100) {
        float acc = linear_b[j];
        #pragma unroll
        for (int t2 = 0; t2 < 10; ++t2) acc = fmaf(za[t2], linear_W[t2 * 100 + j], acc);
        hS[0][b][j] = (f16)acc;
      }
    }
  }
  if (tid < 32) {
    int bb = tid >> 1, ii = tid & 1;
    hS[0][bb][100 + ii] = sdvS[0][bb][ii];
  }
  __syncthreads();

  // Wx frags -> cx, then Wh frags (loop-invariant in regs)
  f16x8 wb[4][4];
  #pragma unroll
  for (int g = 0; g < 4; ++g) {
    int tile = w + 8 * g;
    #pragma unroll
    for (int kf = 0; kf < 4; ++kf)
      wb[g][kf] = *(const f16x8*)(wxb + ((size_t)(tile * 4 + kf) * 64 + l) * 8);
  }
  f32x4 cx[4];
  #pragma unroll
  for (int g = 0; g < 4; ++g) {
    float bpv = bp[(w + 8 * g) * 16 + lr];
    f32x4 c = {bpv, bpv, bpv, bpv};
    cx[g] = c;
  }
  #pragma unroll
  for (int kf = 0; kf < 4; ++kf) {
    f16x8 a = *(const f16x8*)(&hS[0][lr][kf * 32 + lq * 8]);
    #pragma unroll
    for (int g = 0; g < 4; ++g)
      cx[g] = __builtin_amdgcn_mfma_f32_16x16x32_f16(a, wb[g][kf], cx[g], 0, 0, 0);
  }
  #pragma unroll
  for (int g = 0; g < 4; ++g) {
    int tile = w + 8 * g;
    #pragma unroll
    for (int kf = 0; kf < 4; ++kf)
      wb[g][kf] = *(const f16x8*)(whb + ((size_t)(tile * 4 + kf) * 64 + l) * 8);
  }

  const float aw1 = aw[jcol];
  float cst[4];
  #pragma unroll
  for (int r = 0; r < 4; ++r) cst[r] = (float)hS[0][lq * 4 + r][jcol];

  int p = 0;
  for (int t = 0; t < T_STEPS; ++t) {
    // z = cx + [h_{t-1}, sdv_t] @ Whb
    f32x4 z0 = cx[0], z1 = cx[1], z2 = cx[2], z3 = cx[3];
    #pragma unroll
    for (int kf = 0; kf < 4; ++kf) {
      f16x8 a = *(const f16x8*)(&hS[p][lr][kf * 32 + lq * 8]);
      z0 = __builtin_amdgcn_mfma_f32_16x16x32_f16(a, wb[0][kf], z0, 0, 0, 0);
      z1 = __builtin_amdgcn_mfma_f32_16x16x32_f16(a, wb[1][kf], z1, 0, 0, 0);
      z2 = __builtin_amdgcn_mfma_f32_16x16x32_f16(a, wb[2][kf], z2, 0, 0, 0);
      z3 = __builtin_amdgcn_mfma_f32_16x16x32_f16(a, wb[3][kf], z3, 0, 0, 0);
    }
    // gates (lane-local, 4 batches x 1 j)
    float hnew[4], attp[4];
    #pragma unroll
    for (int r = 0; r < 4; ++r) {
      float zi_ = z0[r], zf_ = z1[r], zg_ = z2[r], zo_ = z3[r];
      float ef = __expf(-fmaxf(zf_, -44.f));
      float sf = rcpf(1.f + ef);
      float ea = __expf(-fmaxf(zi_, -44.f));
      float eb = __expf(-2.f * fminf(fmaxf(zg_, -15.f), 15.f));
      float it = (1.f - eb) * rcpf((1.f + ea) * (1.f + eb));
      float cc = fmaf(sf, cst[r], it);
      float eo = __expf(-fmaxf(zo_, -44.f));
      float ec = __expf(-2.f * fminf(fmaxf(cc, -15.f), 15.f));
      float hh = (1.f - ec) * rcpf((1.f + eo) * (1.f + ec));
      cst[r] = cc;
      hnew[r] = hh;
      attp[r] = hh * aw1;   // aw1 = 0 for j >= 100
    }
    // publish h_t (+ sdv_{t+1}) into buffer p^1 — the only pre-barrier work
    if (jcol < 100) {
      #pragma unroll
      for (int r = 0; r < 4; ++r) hS[p ^ 1][lq * 4 + r][jcol] = (f16)hnew[r];
    }
    if (t + 1 < T_STEPS && tid < 32) {
      int bb = tid >> 1, ii = tid & 1;
      hS[p ^ 1][bb][100 + ii] = sdvS[t + 1][bb][ii];
    }
    __syncthreads();  // single barrier per step

    // post-barrier (overlaps next step's MFMA in other waves):
    // reduce attp over lr lanes, publish wave partial for step t
    #pragma unroll
    for (int m = 1; m < 16; m <<= 1) {
      #pragma unroll
      for (int r = 0; r < 4; ++r) attp[r] += __shfl_xor(attp[r], m, 64);
    }
    if (lr == 0) {
      #pragma unroll
      for (int r = 0; r < 4; ++r) part[t & 1][lq * 4 + r][w] = attp[r];
    }
    // wave 0 folds step t-1's partials (written before barrier t-1... visible) -> Pp
    if (tid < 16 && t > 0) {
      int pb = (t - 1) & 1;
      float4 pa = *(const float4*)&part[pb][tid][0];
      float4 pc = *(const float4*)&part[pb][tid][4];
      Pp[(size_t)(t - 1) * B_TOT + b0g + tid] =
          pa.x + pa.y + pa.z + pa.w + pc.x + pc.y + pc.z + pc.w;
    }
    p ^= 1;
  }
  __syncthreads();
  if (tid < 16) {
    int pb = (T_STEPS - 1) & 1;
    float4 pa = *(const float4*)&part[pb][tid][0];
    float4 pc = *(const float4*)&part[pb][tid][4];
    Pp[(size_t)(T_STEPS - 1) * B_TOT + b0g + tid] =
        pa.x + pa.y + pa.z + pa.w + pc.x + pc.y + pc.z + pc.w;
  }
}

__global__ __launch_bounds__(256) void idm_scalar(
    const float* __restrict__ idm_params,
    const float* __restrict__ idm_s,
    const float* __restrict__ att_b,
    const float* __restrict__ noise_f,
    const float* __restrict__ noise_m,
    const float* __restrict__ Pp,
    float* __restrict__ out)
{
  int b = blockIdx.x * 256 + threadIdx.x;  // 0..8191
  const float* P = idm_params + (size_t)b * 5;
  float des_v = P[0], des_tg = P[1], min_jx = P[2], max_a = P[3];
  float inv2s = 0.5f / sqrtf(max_a * P[4]);
  float inv_dv = rcpf(des_v);
  float ego_v = idm_s[(size_t)b * T_STEPS * 8 + 0];
  float ego_x = idm_s[(size_t)b * T_STEPS * 8 + 3];
  float attb = att_b[0];
  float act = 0.f;
  #pragma unroll 8
  for (int t = 0; t < T_STEPS; ++t) {
    const float* s = idm_s + ((size_t)b * T_STEPS + t) * 8;
    float4 s03 = *(const float4*)(s);
    float4 s47 = *(const float4*)(s + 4);
    float nf = noise_f[(size_t)t * B_TOT + b];
    float nm = noise_m[(size_t)t * B_TOT + b];
    float lg = attb + Pp[(size_t)t * B_TOT + b];

    ego_v += act * 0.1f;
    ego_x += ego_v * 0.1f + act * 0.005f;
    float f_v = s03.y, m_v = s03.z, f_x = s47.x, m_x = s47.y, f_ex = s47.z, m_ex = s47.w;
    float af_, am_;
    {
      float dx = fminf(fmaxf(f_x - ego_x, 0.5f), 1000.f);
      float dg = min_jx + fmaxf(0.f, des_tg * ego_v + ego_v * (ego_v - f_v) * inv2s);
      float r = ego_v * inv_dv; float r2 = r * r; float q = dg * rcpf(dx);
      af_ = fminf(fmaxf(max_a * (1.f - r2 * r2 - q * q), -3.f), 3.f);
    }
    {
      float dx = fminf(fmaxf(m_x - ego_x, 0.5f), 1000.f);
      float dg = min_jx + fmaxf(0.f, des_tg * ego_v + ego_v * (ego_v - m_v) * inv2s);
      float r = ego_v * inv_dv; float r2 = r * r; float q = dg * rcpf(dx);
      am_ = fminf(fmaxf(max_a * (1.f - r2 * r2 - q * q), -3.f), 3.f);
    }
    float ef2 = f_ex * af_ + (1.f - f_ex) * nf;
    float em2 = m_ex * am_ + (1.f - m_ex) * nm;
    float eatt = __expf(-fmaxf(5.f * lg, -44.f));
    float att = rcpf(1.f + eatt);
    act = (1.f - att) * ef2 + att * em2;
    out[(size_t)b * T_STEPS + t] = act;
    out[(size_t)B_TOT * T_STEPS + (size_t)b * T_STEPS + t] = att;
  }
}

extern "C" void kernel_launch(void* const* d_in, const int* in_sizes, int n_in,
                              void* d_out, int out_size, void* d_ws, size_t ws_size,
                              hipStream_t stream) {
  const float* z_att      = (const float*)d_in[0];
  const float* idm_params = (const float*)d_in[2];
  const float* idm_s      = (const float*)d_in[3];
  const float* sdv_acts   = (const float*)d_in[4];
  const float* linear_W   = (const float*)d_in[5];
  const float* linear_b   = (const float*)d_in[6];
  const float* lstm_Wx    = (const float*)d_in[7];
  const float* lstm_Wh    = (const float*)d_in[8];
  const float* lstm_b     = (const float*)d_in[9];
  const float* att_W      = (const float*)d_in[10];
  const float* att_b      = (const float*)d_in[11];
  const float* noise_f    = (const float*)d_in[12];
  const float* noise_m    = (const float*)d_in[13];
  float* out = (float*)d_out;

  f16*   whb = (f16*)d_ws;
  f16*   wxb = (f16*)((char*)d_ws + 131072);
  float* bp  = (float*)((char*)d_ws + 262144);
  float* aw  = (float*)((char*)d_ws + 264192);
  float* Pp  = (float*)((char*)d_ws + 294912);

  idm_prep<<<256, 256, 0, stream>>>(lstm_Wx, lstm_Wh, lstm_b, att_W, whb, wxb, bp, aw);
  idm_main<<<B_TOT / NB, 448, 0, stream>>>(z_att, linear_W, linear_b, sdv_acts,
                                           whb, wxb, bp, aw, Pp);
  idm_scalar<<<B_TOT / 256, 256, 0, stream>>>(idm_params, idm_s, att_b,
                                              noise_f, noise_m, Pp, out);
}

// Round 5
// 194.654 us; speedup vs baseline: 5.9784x; 1.1303x over previous
//
#include <hip/hip_runtime.h>
#include <math.h>

// IDMForwardSim R5: logit-via-MFMA + clamp-free gates.
// idm_main: 512 blocks x 448 thr. Per step: 16 z-MFMA + (wave0) 4 logit-MFMA,
//   25-instr/elem gates (exp2-based, no clamps -- inf limits are exact), h write,
//   ONE barrier. No shuffles, no per-step global traffic. Pp bulk-stored at end.
// idm_scalar: 128x64 threads replay the per-batch ego/IDM chain.

#define B_TOT 8192
#define T_STEPS 40
#define NB 16

typedef _Float16 f16;
typedef f16 f16x8 __attribute__((ext_vector_type(8)));
typedef float f32x4 __attribute__((ext_vector_type(4)));

__device__ __forceinline__ float rcpf(float x) { return __builtin_amdgcn_rcpf(x); }
__device__ __forceinline__ float ex2(float x)  { return __builtin_amdgcn_exp2f(x); }
// sigmoid / tanh via exp2; no clamps needed: exp2 -> inf => rcp -> 0 (exact limit)
__device__ __forceinline__ float sigf(float x)  { return rcpf(1.f + ex2(-1.44269504f * x)); }
__device__ __forceinline__ float tanhf_(float x){ return fmaf(-2.f, rcpf(1.f + ex2(2.88539008f * x)), 1.f); }

// ws layout (bytes): whb f16[65536] @0 | wxb f16[65536] @131072 | bp f32[512] @262144
//   | aw f32[128] @264192 | awb f16[2048] @264704 | Pp f32[40][8192] @294912

__global__ __launch_bounds__(256) void idm_prep(
    const float* __restrict__ Wx, const float* __restrict__ Wh,
    const float* __restrict__ bvec, const float* __restrict__ attw,
    f16* __restrict__ whb, f16* __restrict__ wxb,
    float* __restrict__ bp, float* __restrict__ aw, f16* __restrict__ awb)
{
  int i = blockIdx.x * 256 + threadIdx.x;  // 0..65535, i = k*512 + n (coalesced reads)
  int k = i >> 9, n = i & 511;
  int g = n >> 7, j128 = n & 127;
  float vh = 0.f, vx = 0.f;
  if (j128 < 100) {
    int col = g * 100 + j128;
    if (k < 100)      { vh = Wh[k * 400 + col]; vx = Wx[k * 400 + col]; }
    else if (k < 102) { vh = Wx[k * 400 + col]; }  // sdv rows folded into Wh-pad
  }
  // dest B-frag index: tile=n>>4, kf=k>>5, l=((k>>3)&3)*16+(n&15), j=k&7
  int idx = (((n >> 4) * 4 + (k >> 5)) * 64 + (((k >> 3) & 3) * 16 + (n & 15))) * 8 + (k & 7);
  whb[idx] = (f16)vh;
  wxb[idx] = (f16)vx;
  if (i < 512) { int gg = i >> 7, jj = i & 127; bp[i] = (jj < 100) ? bvec[gg * 100 + jj] : 0.f; }
  if (i < 128) aw[i] = (i < 100) ? attw[i] : 0.f;
  if (i < 2048) {  // awb: B-frag tile with col0 = att_W, cols 1..15 = 0
    int j = i & 7, l = (i >> 3) & 63, kf = i >> 9;
    int kk = kf * 32 + ((l >> 4) & 3) * 8 + j;
    int col = l & 15;
    awb[i] = (f16)((col == 0 && kk < 100) ? attw[kk] : 0.f);
  }
}

__global__ __launch_bounds__(448, 4) void idm_main(
    const float* __restrict__ z_att,
    const float* __restrict__ linear_W,
    const float* __restrict__ linear_b,
    const float* __restrict__ sdv_acts,
    const f16* __restrict__ whb, const f16* __restrict__ wxb,
    const float* __restrict__ bp, const f16* __restrict__ awbg,
    float* __restrict__ Pp)
{
  __shared__ f16 hS[2][16][136];        // [buf][batch][k] 0..99 h, 100..101 sdv, pad=0
  __shared__ f16 sdvS[T_STEPS][16][2];
  __shared__ float logitS[T_STEPS][16]; // per-(t,batch) attention logits

  const int tid = threadIdx.x;
  const int w  = tid >> 6;   // 0..6 j-tile
  const int l  = tid & 63;
  const int lr = l & 15;
  const int lq = l >> 4;
  const int b0g = blockIdx.x * NB;
  const int jcol = 16 * w + lr;

  // zero hS (pad rows must stay exact 0)
  for (int idx = tid; idx < 2176; idx += 448) ((unsigned*)hS)[idx] = 0u;
  // stage sdv for all 40 steps (coalesced: 1280 consecutive floats)
  for (int idx = tid; idx < 1280; idx += 448) {
    float v = sdv_acts[(size_t)b0g * 80 + idx];
    int b = idx / 80, r = idx - b * 80;
    sdvS[r >> 1][b][r & 1] = (f16)v;
  }
  __syncthreads();

  // h0 = att_proj into hS[0]
  if (tid < 256) {
    int b = tid >> 4, oct = tid & 15;
    float za[10];
    #pragma unroll
    for (int t2 = 0; t2 < 10; ++t2) za[t2] = z_att[(b0g + b) * 10 + t2];
    #pragma unroll
    for (int jj = 0; jj < 8; ++jj) {
      int j = oct * 8 + jj;
      if (j < 100) {
        float acc = linear_b[j];
        #pragma unroll
        for (int t2 = 0; t2 < 10; ++t2) acc = fmaf(za[t2], linear_W[t2 * 100 + j], acc);
        hS[0][b][j] = (f16)acc;
      }
    }
  }
  if (tid < 32) {
    int bb = tid >> 1, ii = tid & 1;
    hS[0][bb][100 + ii] = sdvS[0][bb][ii];
  }
  __syncthreads();

  // Wx frags -> cx, then Wh frags (loop-invariant in regs)
  f16x8 wb[4][4];
  #pragma unroll
  for (int g = 0; g < 4; ++g) {
    int tile = w + 8 * g;
    #pragma unroll
    for (int kf = 0; kf < 4; ++kf)
      wb[g][kf] = *(const f16x8*)(wxb + ((size_t)(tile * 4 + kf) * 64 + l) * 8);
  }
  f32x4 cx[4];
  #pragma unroll
  for (int g = 0; g < 4; ++g) {
    float bpv = bp[(w + 8 * g) * 16 + lr];
    f32x4 c = {bpv, bpv, bpv, bpv};
    cx[g] = c;
  }
  #pragma unroll
  for (int kf = 0; kf < 4; ++kf) {
    f16x8 a = *(const f16x8*)(&hS[0][lr][kf * 32 + lq * 8]);
    #pragma unroll
    for (int g = 0; g < 4; ++g)
      cx[g] = __builtin_amdgcn_mfma_f32_16x16x32_f16(a, wb[g][kf], cx[g], 0, 0, 0);
  }
  #pragma unroll
  for (int g = 0; g < 4; ++g) {
    int tile = w + 8 * g;
    #pragma unroll
    for (int kf = 0; kf < 4; ++kf)
      wb[g][kf] = *(const f16x8*)(whb + ((size_t)(tile * 4 + kf) * 64 + l) * 8);
  }
  // wave 0: att_W B-frags
  f16x8 awb[4];
  #pragma unroll
  for (int kf = 0; kf < 4; ++kf)
    awb[kf] = *(const f16x8*)(awbg + ((size_t)kf * 64 + l) * 8);

  float cst[4];
  #pragma unroll
  for (int r = 0; r < 4; ++r) cst[r] = (float)hS[0][lq * 4 + r][jcol];

  int p = 0;
  for (int t = 0; t < T_STEPS; ++t) {
    // A-frags for [h_{t}, sdv_t] (loop var t: hS[p] holds h^{(t)})
    f16x8 a0 = *(const f16x8*)(&hS[p][lr][0  + lq * 8]);
    f16x8 a1 = *(const f16x8*)(&hS[p][lr][32 + lq * 8]);
    f16x8 a2 = *(const f16x8*)(&hS[p][lr][64 + lq * 8]);
    f16x8 a3 = *(const f16x8*)(&hS[p][lr][96 + lq * 8]);
    f32x4 z0 = cx[0], z1 = cx[1], z2 = cx[2], z3 = cx[3];
    z0 = __builtin_amdgcn_mfma_f32_16x16x32_f16(a0, wb[0][0], z0, 0, 0, 0);
    z1 = __builtin_amdgcn_mfma_f32_16x16x32_f16(a0, wb[1][0], z1, 0, 0, 0);
    z2 = __builtin_amdgcn_mfma_f32_16x16x32_f16(a0, wb[2][0], z2, 0, 0, 0);
    z3 = __builtin_amdgcn_mfma_f32_16x16x32_f16(a0, wb[3][0], z3, 0, 0, 0);
    z0 = __builtin_amdgcn_mfma_f32_16x16x32_f16(a1, wb[0][1], z0, 0, 0, 0);
    z1 = __builtin_amdgcn_mfma_f32_16x16x32_f16(a1, wb[1][1], z1, 0, 0, 0);
    z2 = __builtin_amdgcn_mfma_f32_16x16x32_f16(a1, wb[2][1], z2, 0, 0, 0);
    z3 = __builtin_amdgcn_mfma_f32_16x16x32_f16(a1, wb[3][1], z3, 0, 0, 0);
    z0 = __builtin_amdgcn_mfma_f32_16x16x32_f16(a2, wb[0][2], z0, 0, 0, 0);
    z1 = __builtin_amdgcn_mfma_f32_16x16x32_f16(a2, wb[1][2], z1, 0, 0, 0);
    z2 = __builtin_amdgcn_mfma_f32_16x16x32_f16(a2, wb[2][2], z2, 0, 0, 0);
    z3 = __builtin_amdgcn_mfma_f32_16x16x32_f16(a2, wb[3][2], z3, 0, 0, 0);
    z0 = __builtin_amdgcn_mfma_f32_16x16x32_f16(a3, wb[0][3], z0, 0, 0, 0);
    z1 = __builtin_amdgcn_mfma_f32_16x16x32_f16(a3, wb[1][3], z1, 0, 0, 0);
    z2 = __builtin_amdgcn_mfma_f32_16x16x32_f16(a3, wb[2][3], z2, 0, 0, 0);
    z3 = __builtin_amdgcn_mfma_f32_16x16x32_f16(a3, wb[3][3], z3, 0, 0, 0);

    // wave 0: logit for output t-1 = h^{(t)} . att_W (same A-frags)
    if (w == 0) {
      f32x4 zA = {0.f, 0.f, 0.f, 0.f};
      zA = __builtin_amdgcn_mfma_f32_16x16x32_f16(a0, awb[0], zA, 0, 0, 0);
      zA = __builtin_amdgcn_mfma_f32_16x16x32_f16(a1, awb[1], zA, 0, 0, 0);
      zA = __builtin_amdgcn_mfma_f32_16x16x32_f16(a2, awb[2], zA, 0, 0, 0);
      zA = __builtin_amdgcn_mfma_f32_16x16x32_f16(a3, awb[3], zA, 0, 0, 0);
      if (t > 0 && lr == 0) {
        #pragma unroll
        for (int r = 0; r < 4; ++r) logitS[t - 1][lq * 4 + r] = zA[r];
      }
    }

    // gates: 4 elements/lane (batch=lq*4+r, j=jcol), clamp-free
    #pragma unroll
    for (int r = 0; r < 4; ++r) {
      float si = sigf(z0[r]);
      float sf = sigf(z1[r]);
      float tg = tanhf_(z2[r]);
      float so = sigf(z3[r]);
      float cc = fmaf(sf, cst[r], si * tg);
      float hh = so * tanhf_(cc);
      cst[r] = cc;
      if (jcol < 100) hS[p ^ 1][lq * 4 + r][jcol] = (f16)hh;
    }
    if (t + 1 < T_STEPS && tid < 32) {
      int bb = tid >> 1, ii = tid & 1;
      hS[p ^ 1][bb][100 + ii] = sdvS[t + 1][bb][ii];
    }
    __syncthreads();  // single barrier per step
    p ^= 1;
  }

  // final logit (t = T-1) from h^{(T)} in hS[p]
  if (w == 0) {
    f16x8 a0 = *(const f16x8*)(&hS[p][lr][0  + lq * 8]);
    f16x8 a1 = *(const f16x8*)(&hS[p][lr][32 + lq * 8]);
    f16x8 a2 = *(const f16x8*)(&hS[p][lr][64 + lq * 8]);
    f16x8 a3 = *(const f16x8*)(&hS[p][lr][96 + lq * 8]);
    f32x4 zA = {0.f, 0.f, 0.f, 0.f};
    zA = __builtin_amdgcn_mfma_f32_16x16x32_f16(a0, awb[0], zA, 0, 0, 0);
    zA = __builtin_amdgcn_mfma_f32_16x16x32_f16(a1, awb[1], zA, 0, 0, 0);
    zA = __builtin_amdgcn_mfma_f32_16x16x32_f16(a2, awb[2], zA, 0, 0, 0);
    zA = __builtin_amdgcn_mfma_f32_16x16x32_f16(a3, awb[3], zA, 0, 0, 0);
    if (lr == 0) {
      #pragma unroll
      for (int r = 0; r < 4; ++r) logitS[T_STEPS - 1][lq * 4 + r] = zA[r];
    }
  }
  __syncthreads();
  // bulk Pp store: 640 floats, 64B per t-row
  for (int idx = tid; idx < T_STEPS * 16; idx += 448) {
    int t = idx >> 4, b = idx & 15;
    Pp[(size_t)t * B_TOT + b0g + b] = logitS[t][b];
  }
}

__global__ __launch_bounds__(64) void idm_scalar(
    const float* __restrict__ idm_params,
    const float* __restrict__ idm_s,
    const float* __restrict__ att_b,
    const float* __restrict__ noise_f,
    const float* __restrict__ noise_m,
    const float* __restrict__ Pp,
    float* __restrict__ out)
{
  int b = blockIdx.x * 64 + threadIdx.x;  // 0..8191
  const float* P = idm_params + (size_t)b * 5;
  float des_v = P[0], des_tg = P[1], min_jx = P[2], max_a = P[3];
  float inv2s = 0.5f / sqrtf(max_a * P[4]);
  float inv_dv = rcpf(des_v);
  float ego_v = idm_s[(size_t)b * T_STEPS * 8 + 0];
  float ego_x = idm_s[(size_t)b * T_STEPS * 8 + 3];
  float attb = att_b[0];
  float act = 0.f;
  #pragma unroll 8
  for (int t = 0; t < T_STEPS; ++t) {
    const float* s = idm_s + ((size_t)b * T_STEPS + t) * 8;
    float4 s03 = *(const float4*)(s);
    float4 s47 = *(const float4*)(s + 4);
    float nf = noise_f[(size_t)t * B_TOT + b];
    float nm = noise_m[(size_t)t * B_TOT + b];
    float lg = attb + Pp[(size_t)t * B_TOT + b];

    ego_v += act * 0.1f;
    ego_x += ego_v * 0.1f + act * 0.005f;
    float f_v = s03.y, m_v = s03.z, f_x = s47.x, m_x = s47.y, f_ex = s47.z, m_ex = s47.w;
    float af_, am_;
    {
      float dx = fminf(fmaxf(f_x - ego_x, 0.5f), 1000.f);
      float dg = min_jx + fmaxf(0.f, des_tg * ego_v + ego_v * (ego_v - f_v) * inv2s);
      float r = ego_v * inv_dv; float r2 = r * r; float q = dg * rcpf(dx);
      af_ = fminf(fmaxf(max_a * (1.f - r2 * r2 - q * q), -3.f), 3.f);
    }
    {
      float dx = fminf(fmaxf(m_x - ego_x, 0.5f), 1000.f);
      float dg = min_jx + fmaxf(0.f, des_tg * ego_v + ego_v * (ego_v - m_v) * inv2s);
      float r = ego_v * inv_dv; float r2 = r * r; float q = dg * rcpf(dx);
      am_ = fminf(fmaxf(max_a * (1.f - r2 * r2 - q * q), -3.f), 3.f);
    }
    float ef2 = f_ex * af_ + (1.f - f_ex) * nf;
    float em2 = m_ex * am_ + (1.f - m_ex) * nm;
    float att = sigf(5.f * lg);
    act = (1.f - att) * ef2 + att * em2;
    out[(size_t)b * T_STEPS + t] = act;
    out[(size_t)B_TOT * T_STEPS + (size_t)b * T_STEPS + t] = att;
  }
}

extern "C" void kernel_launch(void* const* d_in, const int* in_sizes, int n_in,
                              void* d_out, int out_size, void* d_ws, size_t ws_size,
                              hipStream_t stream) {
  const float* z_att      = (const float*)d_in[0];
  const float* idm_params = (const float*)d_in[2];
  const float* idm_s      = (const float*)d_in[3];
  const float* sdv_acts   = (const float*)d_in[4];
  const float* linear_W   = (const float*)d_in[5];
  const float* linear_b   = (const float*)d_in[6];
  const float* lstm_Wx    = (const float*)d_in[7];
  const float* lstm_Wh    = (const float*)d_in[8];
  const float* lstm_b     = (const float*)d_in[9];
  const float* att_W      = (const float*)d_in[10];
  const float* att_b      = (const float*)d_in[11];
  const float* noise_f    = (const float*)d_in[12];
  const float* noise_m    = (const float*)d_in[13];
  float* out = (float*)d_out;

  f16*   whb = (f16*)d_ws;
  f16*   wxb = (f16*)((char*)d_ws + 131072);
  float* bp  = (float*)((char*)d_ws + 262144);
  float* aw  = (float*)((char*)d_ws + 264192);
  f16*   awb = (f16*)((char*)d_ws + 264704);
  float* Pp  = (float*)((char*)d_ws + 294912);

  idm_prep<<<256, 256, 0, stream>>>(lstm_Wx, lstm_Wh, lstm_b, att_W, whb, wxb, bp, aw, awb);
  idm_main<<<B_TOT / NB, 448, 0, stream>>>(z_att, linear_W, linear_b, sdv_acts,
                                           whb, wxb, bp, awb, Pp);
  idm_scalar<<<B_TOT / 64, 64, 0, stream>>>(idm_params, idm_s, att_b,
                                            noise_f, noise_m, Pp, out);
}

// Round 6
// 192.685 us; speedup vs baseline: 6.0395x; 1.0102x over previous
//
#include <hip/hip_runtime.h>
#include <math.h>

// IDMForwardSim R6: R5 main loop + scalar chain folded into a 16-thread block tail.
// idm_main: 512 blocks x 448 thr. Per step: 16 z-MFMA + (wave0) 4 logit-MFMA,
//   clamp-free exp2 gates, h write, ONE barrier. Logits accumulate in LDS; after
//   the final barrier, tid<16 replays the per-batch ego/IDM chain from LDS and
//   writes both outputs. No Pp, no third kernel, no per-step global traffic.

#define B_TOT 8192
#define T_STEPS 40
#define NB 16

typedef _Float16 f16;
typedef f16 f16x8 __attribute__((ext_vector_type(8)));
typedef float f32x4 __attribute__((ext_vector_type(4)));

__device__ __forceinline__ float rcpf(float x) { return __builtin_amdgcn_rcpf(x); }
__device__ __forceinline__ float ex2(float x)  { return __builtin_amdgcn_exp2f(x); }
// sigmoid / tanh via exp2; no clamps needed: exp2 -> inf => rcp -> 0 (exact limit)
__device__ __forceinline__ float sigf(float x)  { return rcpf(1.f + ex2(-1.44269504f * x)); }
__device__ __forceinline__ float tanhf_(float x){ return fmaf(-2.f, rcpf(1.f + ex2(2.88539008f * x)), 1.f); }

// ws layout (bytes): whb f16[65536] @0 | wxb f16[65536] @131072 | bp f32[512] @262144
//   | awb f16[2048] @264192

__global__ __launch_bounds__(256) void idm_prep(
    const float* __restrict__ Wx, const float* __restrict__ Wh,
    const float* __restrict__ bvec, const float* __restrict__ attw,
    f16* __restrict__ whb, f16* __restrict__ wxb,
    float* __restrict__ bp, f16* __restrict__ awb)
{
  int i = blockIdx.x * 256 + threadIdx.x;  // 0..65535, i = k*512 + n (coalesced reads)
  int k = i >> 9, n = i & 511;
  int g = n >> 7, j128 = n & 127;
  float vh = 0.f, vx = 0.f;
  if (j128 < 100) {
    int col = g * 100 + j128;
    if (k < 100)      { vh = Wh[k * 400 + col]; vx = Wx[k * 400 + col]; }
    else if (k < 102) { vh = Wx[k * 400 + col]; }  // sdv rows folded into Wh-pad
  }
  // dest B-frag index: tile=n>>4, kf=k>>5, l=((k>>3)&3)*16+(n&15), j=k&7
  int idx = (((n >> 4) * 4 + (k >> 5)) * 64 + (((k >> 3) & 3) * 16 + (n & 15))) * 8 + (k & 7);
  whb[idx] = (f16)vh;
  wxb[idx] = (f16)vx;
  if (i < 512) { int gg = i >> 7, jj = i & 127; bp[i] = (jj < 100) ? bvec[gg * 100 + jj] : 0.f; }
  if (i < 2048) {  // awb: B-frag tile with col0 = att_W, cols 1..15 = 0
    int j = i & 7, l = (i >> 3) & 63, kf = i >> 9;
    int kk = kf * 32 + ((l >> 4) & 3) * 8 + j;
    int col = l & 15;
    awb[i] = (f16)((col == 0 && kk < 100) ? attw[kk] : 0.f);
  }
}

__global__ __launch_bounds__(448, 4) void idm_main(
    const float* __restrict__ z_att,
    const float* __restrict__ linear_W,
    const float* __restrict__ linear_b,
    const float* __restrict__ sdv_acts,
    const f16* __restrict__ whb, const f16* __restrict__ wxb,
    const float* __restrict__ bp, const f16* __restrict__ awbg,
    const float* __restrict__ idm_params,
    const float* __restrict__ idm_s,
    const float* __restrict__ att_b,
    const float* __restrict__ noise_f,
    const float* __restrict__ noise_m,
    float* __restrict__ out)
{
  __shared__ f16 hS[2][16][136];        // [buf][batch][k] 0..99 h, 100..101 sdv, pad=0
  __shared__ f16 sdvS[T_STEPS][16][2];
  __shared__ float logitS[T_STEPS][16]; // per-(t,batch) attention logits

  const int tid = threadIdx.x;
  const int w  = tid >> 6;   // 0..6 j-tile
  const int l  = tid & 63;
  const int lr = l & 15;
  const int lq = l >> 4;
  const int b0g = blockIdx.x * NB;
  const int jcol = 16 * w + lr;

  // zero hS (pad rows must stay exact 0)
  for (int idx = tid; idx < 2176; idx += 448) ((unsigned*)hS)[idx] = 0u;
  // stage sdv for all 40 steps (coalesced: 1280 consecutive floats)
  for (int idx = tid; idx < 1280; idx += 448) {
    float v = sdv_acts[(size_t)b0g * 80 + idx];
    int b = idx / 80, r = idx - b * 80;
    sdvS[r >> 1][b][r & 1] = (f16)v;
  }
  __syncthreads();

  // h0 = att_proj into hS[0]
  if (tid < 256) {
    int b = tid >> 4, oct = tid & 15;
    float za[10];
    #pragma unroll
    for (int t2 = 0; t2 < 10; ++t2) za[t2] = z_att[(b0g + b) * 10 + t2];
    #pragma unroll
    for (int jj = 0; jj < 8; ++jj) {
      int j = oct * 8 + jj;
      if (j < 100) {
        float acc = linear_b[j];
        #pragma unroll
        for (int t2 = 0; t2 < 10; ++t2) acc = fmaf(za[t2], linear_W[t2 * 100 + j], acc);
        hS[0][b][j] = (f16)acc;
      }
    }
  }
  if (tid < 32) {
    int bb = tid >> 1, ii = tid & 1;
    hS[0][bb][100 + ii] = sdvS[0][bb][ii];
  }
  __syncthreads();

  // Wx frags -> cx, then Wh frags (loop-invariant in regs)
  f16x8 wb[4][4];
  #pragma unroll
  for (int g = 0; g < 4; ++g) {
    int tile = w + 8 * g;
    #pragma unroll
    for (int kf = 0; kf < 4; ++kf)
      wb[g][kf] = *(const f16x8*)(wxb + ((size_t)(tile * 4 + kf) * 64 + l) * 8);
  }
  f32x4 cx[4];
  #pragma unroll
  for (int g = 0; g < 4; ++g) {
    float bpv = bp[(w + 8 * g) * 16 + lr];
    f32x4 c = {bpv, bpv, bpv, bpv};
    cx[g] = c;
  }
  #pragma unroll
  for (int kf = 0; kf < 4; ++kf) {
    f16x8 a = *(const f16x8*)(&hS[0][lr][kf * 32 + lq * 8]);
    #pragma unroll
    for (int g = 0; g < 4; ++g)
      cx[g] = __builtin_amdgcn_mfma_f32_16x16x32_f16(a, wb[g][kf], cx[g], 0, 0, 0);
  }
  #pragma unroll
  for (int g = 0; g < 4; ++g) {
    int tile = w + 8 * g;
    #pragma unroll
    for (int kf = 0; kf < 4; ++kf)
      wb[g][kf] = *(const f16x8*)(whb + ((size_t)(tile * 4 + kf) * 64 + l) * 8);
  }
  // wave 0: att_W B-frags
  f16x8 awb[4];
  #pragma unroll
  for (int kf = 0; kf < 4; ++kf)
    awb[kf] = *(const f16x8*)(awbg + ((size_t)kf * 64 + l) * 8);

  float cst[4];
  #pragma unroll
  for (int r = 0; r < 4; ++r) cst[r] = (float)hS[0][lq * 4 + r][jcol];

  int p = 0;
  for (int t = 0; t < T_STEPS; ++t) {
    // A-frags for [h^{(t)}, sdv_t]
    f16x8 a0 = *(const f16x8*)(&hS[p][lr][0  + lq * 8]);
    f16x8 a1 = *(const f16x8*)(&hS[p][lr][32 + lq * 8]);
    f16x8 a2 = *(const f16x8*)(&hS[p][lr][64 + lq * 8]);
    f16x8 a3 = *(const f16x8*)(&hS[p][lr][96 + lq * 8]);
    f32x4 z0 = cx[0], z1 = cx[1], z2 = cx[2], z3 = cx[3];
    z0 = __builtin_amdgcn_mfma_f32_16x16x32_f16(a0, wb[0][0], z0, 0, 0, 0);
    z1 = __builtin_amdgcn_mfma_f32_16x16x32_f16(a0, wb[1][0], z1, 0, 0, 0);
    z2 = __builtin_amdgcn_mfma_f32_16x16x32_f16(a0, wb[2][0], z2, 0, 0, 0);
    z3 = __builtin_amdgcn_mfma_f32_16x16x32_f16(a0, wb[3][0], z3, 0, 0, 0);
    z0 = __builtin_amdgcn_mfma_f32_16x16x32_f16(a1, wb[0][1], z0, 0, 0, 0);
    z1 = __builtin_amdgcn_mfma_f32_16x16x32_f16(a1, wb[1][1], z1, 0, 0, 0);
    z2 = __builtin_amdgcn_mfma_f32_16x16x32_f16(a1, wb[2][1], z2, 0, 0, 0);
    z3 = __builtin_amdgcn_mfma_f32_16x16x32_f16(a1, wb[3][1], z3, 0, 0, 0);
    z0 = __builtin_amdgcn_mfma_f32_16x16x32_f16(a2, wb[0][2], z0, 0, 0, 0);
    z1 = __builtin_amdgcn_mfma_f32_16x16x32_f16(a2, wb[1][2], z1, 0, 0, 0);
    z2 = __builtin_amdgcn_mfma_f32_16x16x32_f16(a2, wb[2][2], z2, 0, 0, 0);
    z3 = __builtin_amdgcn_mfma_f32_16x16x32_f16(a2, wb[3][2], z3, 0, 0, 0);
    z0 = __builtin_amdgcn_mfma_f32_16x16x32_f16(a3, wb[0][3], z0, 0, 0, 0);
    z1 = __builtin_amdgcn_mfma_f32_16x16x32_f16(a3, wb[1][3], z1, 0, 0, 0);
    z2 = __builtin_amdgcn_mfma_f32_16x16x32_f16(a3, wb[2][3], z2, 0, 0, 0);
    z3 = __builtin_amdgcn_mfma_f32_16x16x32_f16(a3, wb[3][3], z3, 0, 0, 0);

    // wave 0: logit for output t-1 = h^{(t)} . att_W (same A-frags)
    if (w == 0) {
      f32x4 zA = {0.f, 0.f, 0.f, 0.f};
      zA = __builtin_amdgcn_mfma_f32_16x16x32_f16(a0, awb[0], zA, 0, 0, 0);
      zA = __builtin_amdgcn_mfma_f32_16x16x32_f16(a1, awb[1], zA, 0, 0, 0);
      zA = __builtin_amdgcn_mfma_f32_16x16x32_f16(a2, awb[2], zA, 0, 0, 0);
      zA = __builtin_amdgcn_mfma_f32_16x16x32_f16(a3, awb[3], zA, 0, 0, 0);
      if (t > 0 && lr == 0) {
        #pragma unroll
        for (int r = 0; r < 4; ++r) logitS[t - 1][lq * 4 + r] = zA[r];
      }
    }

    // gates: 4 elements/lane (batch=lq*4+r, j=jcol), clamp-free
    #pragma unroll
    for (int r = 0; r < 4; ++r) {
      float si = sigf(z0[r]);
      float sf = sigf(z1[r]);
      float tg = tanhf_(z2[r]);
      float so = sigf(z3[r]);
      float cc = fmaf(sf, cst[r], si * tg);
      float hh = so * tanhf_(cc);
      cst[r] = cc;
      if (jcol < 100) hS[p ^ 1][lq * 4 + r][jcol] = (f16)hh;
    }
    if (t + 1 < T_STEPS && tid < 32) {
      int bb = tid >> 1, ii = tid & 1;
      hS[p ^ 1][bb][100 + ii] = sdvS[t + 1][bb][ii];
    }
    __syncthreads();  // single barrier per step
    p ^= 1;
  }

  // final logit (t = T-1) from h^{(T)} in hS[p]
  if (w == 0) {
    f16x8 a0 = *(const f16x8*)(&hS[p][lr][0  + lq * 8]);
    f16x8 a1 = *(const f16x8*)(&hS[p][lr][32 + lq * 8]);
    f16x8 a2 = *(const f16x8*)(&hS[p][lr][64 + lq * 8]);
    f16x8 a3 = *(const f16x8*)(&hS[p][lr][96 + lq * 8]);
    f32x4 zA = {0.f, 0.f, 0.f, 0.f};
    zA = __builtin_amdgcn_mfma_f32_16x16x32_f16(a0, awb[0], zA, 0, 0, 0);
    zA = __builtin_amdgcn_mfma_f32_16x16x32_f16(a1, awb[1], zA, 0, 0, 0);
    zA = __builtin_amdgcn_mfma_f32_16x16x32_f16(a2, awb[2], zA, 0, 0, 0);
    zA = __builtin_amdgcn_mfma_f32_16x16x32_f16(a3, awb[3], zA, 0, 0, 0);
    if (lr == 0) {
      #pragma unroll
      for (int r = 0; r < 4; ++r) logitS[T_STEPS - 1][lq * 4 + r] = zA[r];
    }
  }
  __syncthreads();

  // ---- tail: per-batch ego/IDM/attention chain, logits straight from LDS ----
  if (tid < 16) {
    int b = b0g + tid;
    const float* P = idm_params + (size_t)b * 5;
    float des_v = P[0], des_tg = P[1], min_jx = P[2], max_a = P[3];
    float inv2s = 0.5f / sqrtf(max_a * P[4]);
    float inv_dv = rcpf(des_v);
    float ego_v = idm_s[(size_t)b * T_STEPS * 8 + 0];
    float ego_x = idm_s[(size_t)b * T_STEPS * 8 + 3];
    float attb = att_b[0];
    float act = 0.f;
    for (int t = 0; t < T_STEPS; ++t) {
      const float* s = idm_s + ((size_t)b * T_STEPS + t) * 8;
      float4 s03 = *(const float4*)(s);
      float4 s47 = *(const float4*)(s + 4);
      float nf = noise_f[(size_t)t * B_TOT + b];
      float nm = noise_m[(size_t)t * B_TOT + b];
      float lg = attb + logitS[t][tid];

      ego_v += act * 0.1f;
      ego_x += ego_v * 0.1f + act * 0.005f;
      float f_v = s03.y, m_v = s03.z, f_x = s47.x, m_x = s47.y, f_ex = s47.z, m_ex = s47.w;
      float af_, am_;
      {
        float dx = fminf(fmaxf(f_x - ego_x, 0.5f), 1000.f);
        float dg = min_jx + fmaxf(0.f, des_tg * ego_v + ego_v * (ego_v - f_v) * inv2s);
        float r = ego_v * inv_dv; float r2 = r * r; float q = dg * rcpf(dx);
        af_ = fminf(fmaxf(max_a * (1.f - r2 * r2 - q * q), -3.f), 3.f);
      }
      {
        float dx = fminf(fmaxf(m_x - ego_x, 0.5f), 1000.f);
        float dg = min_jx + fmaxf(0.f, des_tg * ego_v + ego_v * (ego_v - m_v) * inv2s);
        float r = ego_v * inv_dv; float r2 = r * r; float q = dg * rcpf(dx);
        am_ = fminf(fmaxf(max_a * (1.f - r2 * r2 - q * q), -3.f), 3.f);
      }
      float ef2 = f_ex * af_ + (1.f - f_ex) * nf;
      float em2 = m_ex * am_ + (1.f - m_ex) * nm;
      float att = sigf(5.f * lg);
      act = (1.f - att) * ef2 + att * em2;
      out[(size_t)b * T_STEPS + t] = act;
      out[(size_t)B_TOT * T_STEPS + (size_t)b * T_STEPS + t] = att;
    }
  }
}

extern "C" void kernel_launch(void* const* d_in, const int* in_sizes, int n_in,
                              void* d_out, int out_size, void* d_ws, size_t ws_size,
                              hipStream_t stream) {
  const float* z_att      = (const float*)d_in[0];
  const float* idm_params = (const float*)d_in[2];
  const float* idm_s      = (const float*)d_in[3];
  const float* sdv_acts   = (const float*)d_in[4];
  const float* linear_W   = (const float*)d_in[5];
  const float* linear_b   = (const float*)d_in[6];
  const float* lstm_Wx    = (const float*)d_in[7];
  const float* lstm_Wh    = (const float*)d_in[8];
  const float* lstm_b     = (const float*)d_in[9];
  const float* att_W      = (const float*)d_in[10];
  const float* att_b      = (const float*)d_in[11];
  const float* noise_f    = (const float*)d_in[12];
  const float* noise_m    = (const float*)d_in[13];
  float* out = (float*)d_out;

  f16*   whb = (f16*)d_ws;
  f16*   wxb = (f16*)((char*)d_ws + 131072);
  float* bp  = (float*)((char*)d_ws + 262144);
  f16*   awb = (f16*)((char*)d_ws + 264192);

  idm_prep<<<256, 256, 0, stream>>>(lstm_Wx, lstm_Wh, lstm_b, att_W, whb, wxb, bp, awb);
  idm_main<<<B_TOT / NB, 448, 0, stream>>>(z_att, linear_W, linear_b, sdv_acts,
                                           whb, wxb, bp, awb,
                                           idm_params, idm_s, att_b,
                                           noise_f, noise_m, out);
}